// Round 5
// baseline (461.779 us; speedup 1.0000x reference)
//
#include <hip/hip_runtime.h>
#include <hip/hip_bf16.h>

#define Bn   32
#define Cn   512
#define GCn  128
#define HWn  3136
#define M0   128

#define Q_ELEMS  (Bn*GCn*HWn)     // 12845056 bf16 elems
#define KV_ELEMS (Bn*4*32*32)     // 131072 f32
#define KS_ELEMS (Bn*4*32)        // 4096 f32

typedef __attribute__((ext_vector_type(8))) short bf16x8;
typedef __attribute__((ext_vector_type(4))) float f32x4;

__device__ __forceinline__ float bf2f(unsigned short u) {
    union { unsigned int i; float f; } v; v.i = ((unsigned int)u) << 16; return v.f;
}
__device__ __forceinline__ unsigned short f2bf(float f) {
    union { __hip_bfloat16 h; unsigned short u; } v; v.h = __float2bfloat16(f); return v.u;
}
__device__ __forceinline__ float act_elu1(float v) {
    return v > 0.0f ? v + 1.0f : __expf(v);
}

// ---- pre: wfrag swizzle only (kv/ks zeroing moved to hipMemsetAsync) ----
// wfrag[((mt*4+ks)*64 + l)*8 + j] = W[o=16mt+(l&15)][c=32ks+8*(l>>4)+j]
__global__ __launch_bounds__(256) void k_pre(
    const float* __restrict__ w_qk, unsigned short* __restrict__ wfrag) {
    int idx = blockIdx.x * 256 + threadIdx.x;    // < 32768
    int j  = idx & 7;
    int l  = (idx >> 3) & 63;
    int ks = (idx >> 9) & 3;
    int mt = idx >> 11;
    int o = mt * 16 + (l & 15);
    int c = ks * 32 + (l >> 4) * 8 + j;
    wfrag[idx] = f2bf(w_qk[o * 128 + c]);
}

// ---- fused qk GEMM + elu + kv/ksum (R3-verified version, 439.7us) ----
__device__ __forceinline__ void main_dev(
    const float* __restrict__ x, const unsigned short* __restrict__ wfrag,
    const float* __restrict__ b_qk,
    unsigned short* __restrict__ q_ws, float* __restrict__ kv_g,
    float* __restrict__ ks_g,
    unsigned short* Xn, unsigned short* Klds, int nt, int b) {

    unsigned short* Qlds = Xn;                   // alias: 128*72 = 64*144 = 9216

    const int t  = threadIdx.x;
    const int n0 = nt * 64;
    const float* xa = x + ((long long)(b * Cn + M0)) * HWn;

    // stage 128c x 64n, converting to bf16, transposed [n][c] (stride 144)
    {
        const int c0 = t >> 1, half = t & 1;
        const float* src = xa + (long long)c0 * HWn + n0 + half * 32;
        #pragma unroll
        for (int p = 0; p < 8; ++p) {
            float4 v = *(const float4*)(src + p * 4);
            const int n = half * 32 + p * 4;
            Xn[(n + 0) * 144 + c0] = f2bf(v.x);
            Xn[(n + 1) * 144 + c0] = f2bf(v.y);
            Xn[(n + 2) * 144 + c0] = f2bf(v.z);
            Xn[(n + 3) * 144 + c0] = f2bf(v.w);
        }
    }
    __syncthreads();

    const int w = t >> 6, l = t & 63, nn = l & 15, q = l >> 4;
    f32x4 acc[4][4] = {};     // [im][in]

    #pragma unroll
    for (int ks = 0; ks < 4; ++ks) {
        bf16x8 bq[4];
        #pragma unroll
        for (int in = 0; in < 4; ++in)
            bq[in] = *(const bf16x8*)(Xn + (in * 16 + nn) * 144 + ks * 32 + q * 8);
        #pragma unroll
        for (int im = 0; im < 4; ++im) {
            const int mt = 4 * w + im;
            bf16x8 aq = *(const bf16x8*)(wfrag + ((mt * 4 + ks) * 64 + l) * 8);
            #pragma unroll
            for (int in = 0; in < 4; ++in)
                acc[im][in] = __builtin_amdgcn_mfma_f32_16x16x32_bf16(aq, bq[in], acc[im][in], 0, 0, 0);
        }
    }

    // k epilogue -> Klds (waves 2,3); Xn still live for other waves' GEMM
    if (w >= 2) {
        #pragma unroll
        for (int im = 0; im < 4; ++im) {
            const int obase = w * 64 + im * 16 + q * 4;
            float4 bias4 = *(const float4*)(b_qk + obase);
            const int krow = obase - 128;
            #pragma unroll
            for (int r = 0; r < 4; ++r) {
                const float bias = ((const float*)&bias4)[r];
                #pragma unroll
                for (int in = 0; in < 4; ++in)
                    Klds[(krow + r) * 72 + in * 16 + nn] = f2bf(act_elu1(acc[im][in][r] + bias));
            }
        }
    }
    __syncthreads();   // all GEMM reads of Xn done; Klds complete

    // q epilogue -> Qlds (= Xn space) (waves 0,1)
    if (w < 2) {
        #pragma unroll
        for (int im = 0; im < 4; ++im) {
            const int obase = w * 64 + im * 16 + q * 4;
            float4 bias4 = *(const float4*)(b_qk + obase);
            #pragma unroll
            for (int r = 0; r < 4; ++r) {
                const float bias = ((const float*)&bias4)[r];
                #pragma unroll
                for (int in = 0; in < 4; ++in)
                    Qlds[(obase + r) * 72 + in * 16 + nn] = f2bf(act_elu1(acc[im][in][r] + bias));
            }
        }
    }

    // kv stage: wave w = head h. A-frag from Klds, B-frag (v) from global (hot).
    {
        const int h = w;
        f32x4 akv[2][2] = {};     // [mt(d-tile)][vt(e-tile)]
        float ksl0 = 0.0f, ksl1 = 0.0f;
        #pragma unroll
        for (int kt = 0; kt < 2; ++kt) {
            bf16x8 af0 = *(const bf16x8*)(Klds + (h * 32 + nn) * 72 + kt * 32 + q * 8);
            bf16x8 af1 = *(const bf16x8*)(Klds + (h * 32 + 16 + nn) * 72 + kt * 32 + q * 8);
            {
                const unsigned short* a0 = (const unsigned short*)&af0;
                const unsigned short* a1 = (const unsigned short*)&af1;
                #pragma unroll
                for (int j = 0; j < 8; ++j) { ksl0 += bf2f(a0[j]); ksl1 += bf2f(a1[j]); }
            }
            #pragma unroll
            for (int vt = 0; vt < 2; ++vt) {
                const float* vsrc = xa + (long long)(h * 32 + vt * 16 + nn) * HWn + n0 + kt * 32 + q * 8;
                float4 v0 = *(const float4*)(vsrc);
                float4 v1 = *(const float4*)(vsrc + 4);
                short tb[8];
                tb[0] = (short)f2bf(v0.x); tb[1] = (short)f2bf(v0.y);
                tb[2] = (short)f2bf(v0.z); tb[3] = (short)f2bf(v0.w);
                tb[4] = (short)f2bf(v1.x); tb[5] = (short)f2bf(v1.y);
                tb[6] = (short)f2bf(v1.z); tb[7] = (short)f2bf(v1.w);
                bf16x8 bv = *(bf16x8*)tb;
                akv[0][vt] = __builtin_amdgcn_mfma_f32_16x16x32_bf16(af0, bv, akv[0][vt], 0, 0, 0);
                akv[1][vt] = __builtin_amdgcn_mfma_f32_16x16x32_bf16(af1, bv, akv[1][vt], 0, 0, 0);
            }
        }
        const int bh = b * 4 + h;
        #pragma unroll
        for (int mt = 0; mt < 2; ++mt)
            #pragma unroll
            for (int vt = 0; vt < 2; ++vt)
                #pragma unroll
                for (int r = 0; r < 4; ++r)
                    atomicAdd(&kv_g[(bh << 10) + (mt * 16 + q * 4 + r) * 32 + vt * 16 + nn],
                              akv[mt][vt][r]);
        float s0 = ksl0; s0 += __shfl_xor(s0, 16, 64); s0 += __shfl_xor(s0, 32, 64);
        float s1 = ksl1; s1 += __shfl_xor(s1, 16, 64); s1 += __shfl_xor(s1, 32, 64);
        if (l < 16) {
            atomicAdd(&ks_g[bh * 32 + nn],      s0);
            atomicAdd(&ks_g[bh * 32 + 16 + nn], s1);
        }
    }
    __syncthreads();   // Qlds complete

    // coalesced q write-out: 128 rows x 64 px bf16
    {
        const int row = t >> 1, hf = t & 1;
        const unsigned short* sp = Qlds + row * 72 + hf * 32;
        unsigned short* dp = q_ws + ((long long)(b * GCn + row)) * HWn + n0 + hf * 32;
        #pragma unroll
        for (int p = 0; p < 4; ++p)
            *(bf16x8*)(dp + p * 8) = *(const bf16x8*)(sp + p * 8);
    }
}

// ---- depthwise conv: 2 channels/block, 64-word rows, XOR chunk swizzle,
//      2-row x 8-wide items (KS+1 row-reads serve 2 output rows) ----
template<int KS, int PAD, int CIN>
__device__ __forceinline__ void dwconv2_dev(
    const float* __restrict__ x, const float* __restrict__ wg,
    const float* __restrict__ bg, float* __restrict__ feats,
    float* P, int cp, int b) {

    const int t = threadIdx.x;
    constexpr int ROWS = 56 + 2 * PAD;           // 58 (3x3) / 62 (7x7)
    constexpr int PL = ROWS * 64;                // plane floats
    const int c0 = cp * 2;

    const float4 z4 = make_float4(0.f, 0.f, 0.f, 0.f);
    for (int i = t; i < (2 * PL) >> 2; i += 256) ((float4*)P)[i] = z4;
    __syncthreads();

    for (int i = t; i < 1568; i += 256) {        // stage 2 planes, swizzled
        const int ch = (i >= 784) ? 1 : 0;
        const int r  = i - ch * 784;
        const int y  = r / 14, k = r - y * 14;   // input row y, px 4k..4k+3
        const float* in = x + ((long long)(b * Cn + CIN + c0 + ch)) * HWn + y * 56 + k * 4;
        const int row = y + PAD;
        const int ck  = (1 + k) ^ (row & 7);     // word (4+4k)>>2, XOR-swizzled
        *(float4*)(P + ch * PL + row * 64 + ck * 4) = *(const float4*)in;
    }
    __syncthreads();

    for (int item = t; item < 392; item += 256) {   // 2ch x 28 row-pairs x 7 octs
        const int ch = (item >= 196) ? 1 : 0;
        const int r  = item - ch * 196;
        const int ri = r / 7, m = r - ri * 7;
        const int y0 = ri * 2;
        const int xo = m * 8;
        const float* wp = wg + (c0 + ch) * KS * KS;
        const float bias = bg[c0 + ch];
        const float* Pc = P + ch * PL;
        float* op = feats + ((long long)(b * 384 + (CIN - 128) + c0 + ch)) * HWn;

        float a0[8], a1[8];
        #pragma unroll
        for (int j = 0; j < 8; ++j) { a0[j] = bias; a1[j] = bias; }
        #pragma unroll
        for (int dy = 0; dy <= KS; ++dy) {
            const int row = y0 + dy;
            float rr[16];
            #pragma unroll
            for (int u = 0; u < 4; ++u) {
                const int ck = ((xo >> 2) + u) ^ (row & 7);
                *(float4*)(rr + 4 * u) = *(const float4*)(Pc + row * 64 + ck * 4);
            }
            if (dy < KS) {
                #pragma unroll
                for (int dx = 0; dx < KS; ++dx) {
                    const float wv = wp[dy * KS + dx];
                    #pragma unroll
                    for (int j = 0; j < 8; ++j)
                        a0[j] = __builtin_fmaf(wv, rr[j + dx + 4 - PAD], a0[j]);
                }
            }
            if (dy >= 1) {
                #pragma unroll
                for (int dx = 0; dx < KS; ++dx) {
                    const float wv = wp[(dy - 1) * KS + dx];
                    #pragma unroll
                    for (int j = 0; j < 8; ++j)
                        a1[j] = __builtin_fmaf(wv, rr[j + dx + 4 - PAD], a1[j]);
                }
            }
        }
        *(float4*)(op + y0 * 56 + xo)           = make_float4(a0[0], a0[1], a0[2], a0[3]);
        *(float4*)(op + y0 * 56 + xo + 4)       = make_float4(a0[4], a0[5], a0[6], a0[7]);
        *(float4*)(op + (y0 + 1) * 56 + xo)     = make_float4(a1[0], a1[1], a1[2], a1[3]);
        *(float4*)(op + (y0 + 1) * 56 + xo + 4) = make_float4(a1[4], a1[5], a1[6], a1[7]);
    }
}

// ---- k_big: main (0..1567) | dw2 (1568..3615) | dw1 (3616..5663) |
//             copy (5664..7711). All mutually independent. ----
__global__ __launch_bounds__(256) void k_big(
    const float* __restrict__ x, const unsigned short* __restrict__ wfrag,
    const float* __restrict__ b_qk,
    unsigned short* __restrict__ q_ws, float* __restrict__ kv_g,
    float* __restrict__ ks_g,
    const float* __restrict__ w_dw1, const float* __restrict__ b_dw1,
    const float* __restrict__ w_dw2, const float* __restrict__ b_dw2,
    float* __restrict__ mem_out, float* __restrict__ feats) {

    __shared__ __align__(16) unsigned char smem[36864];
    const int bid = blockIdx.x;

    if (bid < 1568) {
        main_dev(x, wfrag, b_qk, q_ws, kv_g, ks_g,
                 (unsigned short*)smem, (unsigned short*)(smem + 18432),
                 bid % 49, bid / 49);
    } else if (bid < 3616) {
        const int r = bid - 1568;
        dwconv2_dev<7, 3, 384>(x, w_dw2, b_dw2, feats, (float*)smem, r & 63, r >> 6);
    } else if (bid < 5664) {
        const int r = bid - 3616;
        dwconv2_dev<3, 1, 256>(x, w_dw1, b_dw1, feats, (float*)smem, r & 63, r >> 6);
    } else {
        const int r = bid - 5664;                // 2048 copy blocks
        for (int i4 = r * 256 + (int)threadIdx.x; i4 < 3211264; i4 += 2048 * 256) {
            int b  = i4 / 100352;
            int rr = i4 - b * 100352;
            ((float4*)mem_out)[i4] = ((const float4*)x)[(long long)b * 401408 + rr];
        }
    }
}

// ---- k_att: attention epilogue (depends on q_ws, kv_g, ks_g) ----
__global__ __launch_bounds__(256) void k_att(
    const unsigned short* __restrict__ q_ws, const float* __restrict__ kv_g,
    const float* __restrict__ ks_g, float* __restrict__ feats) {

    __shared__ float kvl[1024];
    __shared__ float kml[32];
    const int t = threadIdx.x;
    const int r = blockIdx.x;                    // 896 blocks
    const int b = r / 28, rem = r % 28;
    const int gx = rem % 7, h = rem / 7;
    const int bh = b * 4 + h;
    const float inv = 1.0f / 3136.0f;
    #pragma unroll
    for (int p = 0; p < 4; ++p) kvl[t + p * 256] = kv_g[(bh << 10) + t + p * 256] * inv;
    if (t < 32) kml[t] = ks_g[bh * 32 + t] * inv;
    __syncthreads();

    const int n2 = gx * 256 + t;
    if (n2 >= 1568) return;
    const unsigned short* qp = q_ws + ((long long)(b * GCn + h * 32)) * HWn + n2 * 2;
    float a0[32], a1[32];
    float z0 = 1e-6f, z1 = 1e-6f;
    #pragma unroll
    for (int e = 0; e < 32; ++e) { a0[e] = 0.f; a1[e] = 0.f; }
    #pragma unroll 4
    for (int d = 0; d < 32; ++d) {
        const unsigned int qq = *(const unsigned int*)(qp + (long long)d * HWn);
        const float q0 = bf2f((unsigned short)qq);
        const float q1 = bf2f((unsigned short)(qq >> 16));
        z0 = __builtin_fmaf(q0, kml[d], z0);
        z1 = __builtin_fmaf(q1, kml[d], z1);
        #pragma unroll
        for (int e = 0; e < 32; ++e) {
            const float kv = kvl[d * 32 + e];
            a0[e] = __builtin_fmaf(q0, kv, a0[e]);
            a1[e] = __builtin_fmaf(q1, kv, a1[e]);
        }
    }
    z0 = 1.f / z0; z1 = 1.f / z1;
    float* op = feats + ((long long)(b * 384 + h * 32)) * HWn + n2 * 2;
    #pragma unroll
    for (int e = 0; e < 32; ++e)
        *(float2*)(op + (long long)e * HWn) = make_float2(a0[e] * z0, a1[e] * z1);
}

extern "C" void kernel_launch(void* const* d_in, const int* in_sizes, int n_in,
                              void* d_out, int out_size, void* d_ws, size_t ws_size,
                              hipStream_t stream) {
    const float* x     = (const float*)d_in[0];
    const float* w_dw1 = (const float*)d_in[1];
    const float* b_dw1 = (const float*)d_in[2];
    const float* w_dw2 = (const float*)d_in[3];
    const float* b_dw2 = (const float*)d_in[4];
    const float* w_qk  = (const float*)d_in[5];
    const float* b_qk  = (const float*)d_in[6];
    float* out = (float*)d_out;

    // ws layout: q bf16 | kv f32 | ksum f32 | wfrag bf16
    unsigned short* q_ws = (unsigned short*)d_ws;
    float* kv_g = (float*)(q_ws + (long long)Q_ELEMS);
    float* ks_g = kv_g + KV_ELEMS;
    unsigned short* wfrag = (unsigned short*)(ks_g + KS_ELEMS);

    float* mem_out = out;
    float* feats   = out + (long long)Bn * GCn * HWn;

    hipMemsetAsync(kv_g, 0, (KV_ELEMS + KS_ELEMS) * sizeof(float), stream);
    k_pre<<<128, 256, 0, stream>>>(w_qk, wfrag);
    k_big<<<7712, 256, 0, stream>>>(x, wfrag, b_qk, q_ws, kv_g, ks_g,
                                    w_dw1, b_dw1, w_dw2, b_dw2, mem_out, feats);
    k_att<<<896, 256, 0, stream>>>(q_ws, kv_g, ks_g, feats);
}

// Round 7
// 423.448 us; speedup vs baseline: 1.0905x; 1.0905x over previous
//
#include <hip/hip_runtime.h>
#include <hip/hip_bf16.h>

#define Bn   32
#define Cn   512
#define GCn  128
#define HWn  3136
#define M0   128

#define Q_ELEMS  (Bn*GCn*HWn)     // 12845056 bf16 elems
#define KV_ELEMS (Bn*4*32*32)     // 131072 f32
#define KS_ELEMS (Bn*4*32)        // 4096 f32

typedef __attribute__((ext_vector_type(8))) short bf16x8;
typedef __attribute__((ext_vector_type(4))) float f32x4;
typedef __attribute__((ext_vector_type(4))) float nf4;   // native vecs for NT builtins
typedef __attribute__((ext_vector_type(2))) float nf2;

__device__ __forceinline__ float bf2f(unsigned short u) {
    union { unsigned int i; float f; } v; v.i = ((unsigned int)u) << 16; return v.f;
}
__device__ __forceinline__ unsigned short f2bf(float f) {
    union { __hip_bfloat16 h; unsigned short u; } v; v.h = __float2bfloat16(f); return v.u;
}
__device__ __forceinline__ float act_elu1(float v) {
    return v > 0.0f ? v + 1.0f : __expf(v);
}
__device__ __forceinline__ void nt_store4(float* p, float a, float b, float c, float d) {
    nf4 v; v.x = a; v.y = b; v.z = c; v.w = d;
    __builtin_nontemporal_store(v, (nf4*)p);
}
__device__ __forceinline__ void nt_store2(float* p, float a, float b) {
    nf2 v; v.x = a; v.y = b;
    __builtin_nontemporal_store(v, (nf2*)p);
}

// ---- pre: wfrag swizzle (blocks 0..127) + zero kv/ksum (blocks 128..655) ----
// wfrag[((mt*4+ks)*64 + l)*8 + j] = W[o=16mt+(l&15)][c=32ks+8*(l>>4)+j]
__global__ __launch_bounds__(256) void k_pre(
    const float* __restrict__ w_qk, unsigned short* __restrict__ wfrag,
    float* __restrict__ kvz) {
    const int t = threadIdx.x;
    if (blockIdx.x < 128) {
        int idx = blockIdx.x * 256 + t;          // < 32768
        int j  = idx & 7;
        int l  = (idx >> 3) & 63;
        int ks = (idx >> 9) & 3;
        int mt = idx >> 11;
        int o = mt * 16 + (l & 15);
        int c = ks * 32 + (l >> 4) * 8 + j;
        wfrag[idx] = f2bf(w_qk[o * 128 + c]);
    } else {
        int i = (blockIdx.x - 128) * 256 + t;    // 528*256 = 135168 exactly
        kvz[i] = 0.0f;
    }
}

// ---- fused qk GEMM + elu + kv/ksum (R3-verified structure) ----
// Staging: lane = channel-pair, wave = 16-px segment -> ds_write_b32,
// 2-way bank access (free), identical LDS image to R3.
__device__ __forceinline__ void main_dev(
    const float* __restrict__ x, const unsigned short* __restrict__ wfrag,
    const float* __restrict__ b_qk,
    unsigned short* __restrict__ q_ws, float* __restrict__ kv_g,
    float* __restrict__ ks_g,
    unsigned short* Xn, unsigned short* Klds, int nt, int b) {

    unsigned short* Qlds = Xn;                   // alias: 128*72 = 64*144 = 9216

    const int t  = threadIdx.x;
    const int n0 = nt * 64;
    const float* xa = x + ((long long)(b * Cn + M0)) * HWn;

    // stage 128c x 64n, bf16, transposed [n][c] (stride 144), packed b32 writes
    {
        const int cpair = t & 63;                // channels 2cpair, 2cpair+1
        const int seg   = t >> 6;                // px n = seg*16 + i
        const float* s0 = xa + (long long)(2 * cpair) * HWn + n0 + seg * 16;
        const float* s1 = s0 + HWn;
        #pragma unroll
        for (int u = 0; u < 4; ++u) {
            float4 a  = *(const float4*)(s0 + 4 * u);
            float4 b2 = *(const float4*)(s1 + 4 * u);
            const float av[4] = {a.x, a.y, a.z, a.w};
            const float bv[4] = {b2.x, b2.y, b2.z, b2.w};
            #pragma unroll
            for (int j = 0; j < 4; ++j) {
                const int n = seg * 16 + 4 * u + j;
                unsigned int pk = (unsigned int)f2bf(av[j]) |
                                  ((unsigned int)f2bf(bv[j]) << 16);
                *(unsigned int*)(Xn + n * 144 + 2 * cpair) = pk;
            }
        }
    }
    __syncthreads();

    const int w = t >> 6, l = t & 63, nn = l & 15, q = l >> 4;
    f32x4 acc[4][4] = {};     // [im][in]

    #pragma unroll
    for (int ks = 0; ks < 4; ++ks) {
        bf16x8 bq[4];
        #pragma unroll
        for (int in = 0; in < 4; ++in)
            bq[in] = *(const bf16x8*)(Xn + (in * 16 + nn) * 144 + ks * 32 + q * 8);
        #pragma unroll
        for (int im = 0; im < 4; ++im) {
            const int mt = 4 * w + im;
            bf16x8 aq = *(const bf16x8*)(wfrag + ((mt * 4 + ks) * 64 + l) * 8);
            #pragma unroll
            for (int in = 0; in < 4; ++in)
                acc[im][in] = __builtin_amdgcn_mfma_f32_16x16x32_bf16(aq, bq[in], acc[im][in], 0, 0, 0);
        }
    }

    // k epilogue -> Klds (waves 2,3); Xn still live for other waves' GEMM
    if (w >= 2) {
        #pragma unroll
        for (int im = 0; im < 4; ++im) {
            const int obase = w * 64 + im * 16 + q * 4;
            float4 bias4 = *(const float4*)(b_qk + obase);
            const int krow = obase - 128;
            #pragma unroll
            for (int r = 0; r < 4; ++r) {
                const float bias = ((const float*)&bias4)[r];
                #pragma unroll
                for (int in = 0; in < 4; ++in)
                    Klds[(krow + r) * 72 + in * 16 + nn] = f2bf(act_elu1(acc[im][in][r] + bias));
            }
        }
    }
    __syncthreads();   // all GEMM reads of Xn done; Klds complete

    // q epilogue -> Qlds (= Xn space) (waves 0,1)
    if (w < 2) {
        #pragma unroll
        for (int im = 0; im < 4; ++im) {
            const int obase = w * 64 + im * 16 + q * 4;
            float4 bias4 = *(const float4*)(b_qk + obase);
            #pragma unroll
            for (int r = 0; r < 4; ++r) {
                const float bias = ((const float*)&bias4)[r];
                #pragma unroll
                for (int in = 0; in < 4; ++in)
                    Qlds[(obase + r) * 72 + in * 16 + nn] = f2bf(act_elu1(acc[im][in][r] + bias));
            }
        }
    }

    // kv stage: wave w = head h. A-frag from Klds, B-frag (v) from global (hot).
    {
        const int h = w;
        f32x4 akv[2][2] = {};     // [mt(d-tile)][vt(e-tile)]
        float ksl0 = 0.0f, ksl1 = 0.0f;
        #pragma unroll
        for (int kt = 0; kt < 2; ++kt) {
            bf16x8 af0 = *(const bf16x8*)(Klds + (h * 32 + nn) * 72 + kt * 32 + q * 8);
            bf16x8 af1 = *(const bf16x8*)(Klds + (h * 32 + 16 + nn) * 72 + kt * 32 + q * 8);
            {
                const unsigned short* a0 = (const unsigned short*)&af0;
                const unsigned short* a1 = (const unsigned short*)&af1;
                #pragma unroll
                for (int j = 0; j < 8; ++j) { ksl0 += bf2f(a0[j]); ksl1 += bf2f(a1[j]); }
            }
            #pragma unroll
            for (int vt = 0; vt < 2; ++vt) {
                const float* vsrc = xa + (long long)(h * 32 + vt * 16 + nn) * HWn + n0 + kt * 32 + q * 8;
                float4 v0 = *(const float4*)(vsrc);
                float4 v1 = *(const float4*)(vsrc + 4);
                short tb[8];
                tb[0] = (short)f2bf(v0.x); tb[1] = (short)f2bf(v0.y);
                tb[2] = (short)f2bf(v0.z); tb[3] = (short)f2bf(v0.w);
                tb[4] = (short)f2bf(v1.x); tb[5] = (short)f2bf(v1.y);
                tb[6] = (short)f2bf(v1.z); tb[7] = (short)f2bf(v1.w);
                bf16x8 bv = *(bf16x8*)tb;
                akv[0][vt] = __builtin_amdgcn_mfma_f32_16x16x32_bf16(af0, bv, akv[0][vt], 0, 0, 0);
                akv[1][vt] = __builtin_amdgcn_mfma_f32_16x16x32_bf16(af1, bv, akv[1][vt], 0, 0, 0);
            }
        }
        const int bh = b * 4 + h;
        #pragma unroll
        for (int mt = 0; mt < 2; ++mt)
            #pragma unroll
            for (int vt = 0; vt < 2; ++vt)
                #pragma unroll
                for (int r = 0; r < 4; ++r)
                    atomicAdd(&kv_g[(bh << 10) + (mt * 16 + q * 4 + r) * 32 + vt * 16 + nn],
                              akv[mt][vt][r]);
        float s0 = ksl0; s0 += __shfl_xor(s0, 16, 64); s0 += __shfl_xor(s0, 32, 64);
        float s1 = ksl1; s1 += __shfl_xor(s1, 16, 64); s1 += __shfl_xor(s1, 32, 64);
        if (l < 16) {
            atomicAdd(&ks_g[bh * 32 + nn],      s0);
            atomicAdd(&ks_g[bh * 32 + 16 + nn], s1);
        }
    }
    __syncthreads();   // Qlds complete

    // coalesced q write-out: 128 rows x 64 px bf16
    {
        const int row = t >> 1, hf = t & 1;
        const unsigned short* sp = Qlds + row * 72 + hf * 32;
        unsigned short* dp = q_ws + ((long long)(b * GCn + row)) * HWn + n0 + hf * 32;
        #pragma unroll
        for (int p = 0; p < 4; ++p)
            *(bf16x8*)(dp + p * 8) = *(const bf16x8*)(sp + p * 8);
    }
}

// ---- k2: main blocks (0..1567) + mem-copy blocks (1568..3615) ----
__global__ __launch_bounds__(256) void k_maincopy(
    const float* __restrict__ x, const unsigned short* __restrict__ wfrag,
    const float* __restrict__ b_qk,
    unsigned short* __restrict__ q_ws, float* __restrict__ kv_g,
    float* __restrict__ ks_g, float* __restrict__ mem_out) {

    __shared__ __align__(16) unsigned char smem[36864];  // Xn 18432 | Klds 18432
    const int bid = blockIdx.x;
    if (bid < 1568) {
        main_dev(x, wfrag, b_qk, q_ws, kv_g, ks_g,
                 (unsigned short*)smem, (unsigned short*)(smem + 18432),
                 bid % 49, bid / 49);
    } else {
        const int r = bid - 1568;                // 2048 copy blocks, NT both ways
        for (int i4 = r * 256 + (int)threadIdx.x; i4 < 3211264; i4 += 2048 * 256) {
            int b  = i4 / 100352;
            int rr = i4 - b * 100352;
            nf4 v = __builtin_nontemporal_load(((const nf4*)x) + (long long)b * 401408 + rr);
            __builtin_nontemporal_store(v, ((nf4*)mem_out) + i4);
        }
    }
}

// ---- att epilogue: 2 pixels/thread, q bf16, kv broadcast from LDS ----
__device__ __forceinline__ void att_dev(
    const unsigned short* __restrict__ q_ws, const float* __restrict__ kv_g,
    const float* __restrict__ ks_g, float* __restrict__ feats,
    float* kvl, float* kml, int gx, int h, int b) {

    const int t = threadIdx.x;
    const int bh = b * 4 + h;
    const float inv = 1.0f / 3136.0f;
    #pragma unroll
    for (int p = 0; p < 4; ++p) kvl[t + p * 256] = kv_g[(bh << 10) + t + p * 256] * inv;
    if (t < 32) kml[t] = ks_g[bh * 32 + t] * inv;
    __syncthreads();

    const int n2 = gx * 256 + t;
    if (n2 >= 1568) return;
    const unsigned short* qp = q_ws + ((long long)(b * GCn + h * 32)) * HWn + n2 * 2;
    float a0[32], a1[32];
    float z0 = 1e-6f, z1 = 1e-6f;
    #pragma unroll
    for (int e = 0; e < 32; ++e) { a0[e] = 0.f; a1[e] = 0.f; }
    #pragma unroll 4
    for (int d = 0; d < 32; ++d) {
        const unsigned int qq = *(const unsigned int*)(qp + (long long)d * HWn);
        const float q0 = bf2f((unsigned short)qq);
        const float q1 = bf2f((unsigned short)(qq >> 16));
        z0 = __builtin_fmaf(q0, kml[d], z0);
        z1 = __builtin_fmaf(q1, kml[d], z1);
        #pragma unroll
        for (int e = 0; e < 32; ++e) {
            const float kv = kvl[d * 32 + e];
            a0[e] = __builtin_fmaf(q0, kv, a0[e]);
            a1[e] = __builtin_fmaf(q1, kv, a1[e]);
        }
    }
    z0 = 1.f / z0; z1 = 1.f / z1;
    float* op = feats + ((long long)(b * 384 + h * 32)) * HWn + n2 * 2;
    #pragma unroll
    for (int e = 0; e < 32; ++e)
        nt_store2(op + (long long)e * HWn, a0[e] * z0, a1[e] * z1);
}

// ---- depthwise conv: 2 channels/block, 64-word rows, XOR chunk swizzle.
//      Single-pass staging: halo slots write zero, interior writes data. ----
template<int KS, int PAD, int CIN>
__device__ __forceinline__ void dwconv2_dev(
    const float* __restrict__ x, const float* __restrict__ wg,
    const float* __restrict__ bg, float* __restrict__ feats,
    float* P, int cp, int b) {

    const int t = threadIdx.x;
    constexpr int ROWS = 56 + 2 * PAD;           // 58 (3x3) / 62 (7x7)
    constexpr int PL = ROWS * 64;                // plane floats
    const int c0 = cp * 2;
    const float4 z4 = make_float4(0.f, 0.f, 0.f, 0.f);

    // one pass: logical chunk m 0..15 per row; m==0/15 or OOB row -> zero
    for (int i = t; i < 2 * ROWS * 16; i += 256) {
        const int ch  = (i >= ROWS * 16) ? 1 : 0;
        const int r   = i - ch * ROWS * 16;
        const int row = r >> 4, m = r & 15;
        const int y   = row - PAD;
        float4 v = z4;
        if (m >= 1 && m <= 14 && y >= 0 && y < 56)
            v = *(const float4*)(x + ((long long)(b * Cn + CIN + c0 + ch)) * HWn + y * 56 + (m - 1) * 4);
        *(float4*)(P + ch * PL + row * 64 + ((m ^ (row & 7)) << 2)) = v;
    }
    __syncthreads();

    for (int item = t; item < 392; item += 256) {   // 2ch x 28 row-pairs x 7 octs
        const int ch = (item >= 196) ? 1 : 0;
        const int r  = item - ch * 196;
        const int ri = r / 7, m = r - ri * 7;
        const int y0 = ri * 2;
        const int xo = m * 8;
        const float* wp = wg + (c0 + ch) * KS * KS;
        const float bias = bg[c0 + ch];
        const float* Pc = P + ch * PL;
        float* op = feats + ((long long)(b * 384 + (CIN - 128) + c0 + ch)) * HWn;

        float a0[8], a1[8];
        #pragma unroll
        for (int j = 0; j < 8; ++j) { a0[j] = bias; a1[j] = bias; }
        #pragma unroll
        for (int dy = 0; dy <= KS; ++dy) {
            const int row = y0 + dy;
            float rr[16];
            #pragma unroll
            for (int u = 0; u < 4; ++u) {
                const int ck = ((xo >> 2) + u) ^ (row & 7);
                *(float4*)(rr + 4 * u) = *(const float4*)(Pc + row * 64 + ck * 4);
            }
            if (dy < KS) {
                #pragma unroll
                for (int dx = 0; dx < KS; ++dx) {
                    const float wv = wp[dy * KS + dx];
                    #pragma unroll
                    for (int j = 0; j < 8; ++j)
                        a0[j] = __builtin_fmaf(wv, rr[j + dx + 4 - PAD], a0[j]);
                }
            }
            if (dy >= 1) {
                #pragma unroll
                for (int dx = 0; dx < KS; ++dx) {
                    const float wv = wp[(dy - 1) * KS + dx];
                    #pragma unroll
                    for (int j = 0; j < 8; ++j)
                        a1[j] = __builtin_fmaf(wv, rr[j + dx + 4 - PAD], a1[j]);
                }
            }
        }
        nt_store4(op + y0 * 56 + xo,           a0[0], a0[1], a0[2], a0[3]);
        nt_store4(op + y0 * 56 + xo + 4,       a0[4], a0[5], a0[6], a0[7]);
        nt_store4(op + (y0 + 1) * 56 + xo,     a1[0], a1[1], a1[2], a1[3]);
        nt_store4(op + (y0 + 1) * 56 + xo + 4, a1[4], a1[5], a1[6], a1[7]);
    }
}

// ---- k3: dw2 (0..2047) | dw1 (2048..4095) | att (4096..4991) ----
__global__ __launch_bounds__(256) void k_post2(
    const float* __restrict__ x,
    const unsigned short* __restrict__ q_ws, const float* __restrict__ kv_g,
    const float* __restrict__ ks_g,
    const float* __restrict__ w_dw1, const float* __restrict__ b_dw1,
    const float* __restrict__ w_dw2, const float* __restrict__ b_dw2,
    float* __restrict__ feats) {

    __shared__ __align__(16) float smem[2 * 62 * 64];   // 31744 B
    const int bid = blockIdx.x;

    if (bid < 2048) {
        dwconv2_dev<7, 3, 384>(x, w_dw2, b_dw2, feats, smem, bid & 63, bid >> 6);
    } else if (bid < 4096) {
        const int r = bid - 2048;
        dwconv2_dev<3, 1, 256>(x, w_dw1, b_dw1, feats, smem, r & 63, r >> 6);
    } else {
        const int r = bid - 4096;                // 896 att blocks
        const int b = r / 28, rem = r % 28;
        att_dev(q_ws, kv_g, ks_g, feats, smem, smem + 1024, rem % 7, rem / 7, b);
    }
}

extern "C" void kernel_launch(void* const* d_in, const int* in_sizes, int n_in,
                              void* d_out, int out_size, void* d_ws, size_t ws_size,
                              hipStream_t stream) {
    const float* x     = (const float*)d_in[0];
    const float* w_dw1 = (const float*)d_in[1];
    const float* b_dw1 = (const float*)d_in[2];
    const float* w_dw2 = (const float*)d_in[3];
    const float* b_dw2 = (const float*)d_in[4];
    const float* w_qk  = (const float*)d_in[5];
    const float* b_qk  = (const float*)d_in[6];
    float* out = (float*)d_out;

    // ws layout: q bf16 | kv f32 | ksum f32 | wfrag bf16
    unsigned short* q_ws = (unsigned short*)d_ws;
    float* kv_g = (float*)(q_ws + (long long)Q_ELEMS);
    float* ks_g = kv_g + KV_ELEMS;
    unsigned short* wfrag = (unsigned short*)(ks_g + KS_ELEMS);

    float* mem_out = out;
    float* feats   = out + (long long)Bn * GCn * HWn;

    k_pre     <<<656, 256, 0, stream>>>(w_qk, wfrag, kv_g);
    k_maincopy<<<3616, 256, 0, stream>>>(x, wfrag, b_qk, q_ws, kv_g, ks_g, mem_out);
    k_post2   <<<4992, 256, 0, stream>>>(x, q_ws, kv_g, ks_g,
                                         w_dw1, b_dw1, w_dw2, b_dw2, feats);
}